// Round 5
// baseline (3010.388 us; speedup 1.0000x reference)
//
#include <hip/hip_runtime.h>
#include <hip/hip_bf16.h>
#include <math.h>

// ------------------------------------------------------------------
// CRvNN forward on MI355X. Round 5: 1024-thread blocks (16 waves,
// 4 waves/SIMD) to hide L2 weight-load latency; merged phase schedule
// (L2 || R2 || c1) -> 6 barriers/step. State in LDS (160,768 B).
// ------------------------------------------------------------------

typedef __bf16 bf16;
typedef bf16  bf16x8 __attribute__((ext_vector_type(8)));
typedef float f32x4  __attribute__((ext_vector_type(4)));

#define MFMA16(a,b,c) __builtin_amdgcn_mfma_f32_16x16x32_bf16((a),(b),(c),0,0,0)

constexpr int LDB = 264;  // bf16 row stride for 256-wide tiles
constexpr int LDI = 520;  // bf16 row stride for 512-wide inter
constexpr int LDP = 40;   // bf16 row stride for 32x32 prob mats

// LDS arena byte offsets (total 160768 <= 163840)
constexpr int OFF_SEQ   = 0;        // f32 [32][256]  32768
constexpr int OFF_SEQB  = 32768;    // bf16 [32][264] 16896
constexpr int OFF_L1    = 49664;    // bf16 [32][264] 16896
constexpr int OFF_R1    = 66560;    // bf16 [32][264] 16896 } sTrans f32 aliases
constexpr int OFF_TMP   = 83456;    // bf16 [32][264] 16896 } R1+TMP (dead by then)
constexpr int OFF_TRANS = 66560;    // f32 [32][256]  32768 (alias)
constexpr int OFF_INTER = 100352;   // bf16 [32][520] 33280
constexpr int OFF_TMP2  = 133632;   // bf16 [32][264] 16896
constexpr int OFF_LP    = 150528;   // f32 [32][32]   4096 (for consumed matvec)
constexpr int OFF_LPB   = 154624;   // bf16 [32][40]  2560
constexpr int OFF_RPB   = 157184;   // bf16 [32][40]  2560
constexpr int OFF_ACT   = 159744;   // f32 [32]
constexpr int OFF_TP    = 159872;
constexpr int OFF_TS    = 160000;
constexpr int OFF_IM    = 160128;
constexpr int OFF_SELP  = 160256;
constexpr int OFF_LTM   = 160384;
constexpr int OFF_ENDM  = 160512;
constexpr int OFF_REM   = 160640;
constexpr int SMEM_BYTES = 160768;

__device__ __forceinline__ float gelu_f(float v) {
    return 0.5f * v * (1.0f + erff(v * 0.70710678118654752f));
}
__device__ __forceinline__ float sigm_f(float v) {
    return 1.0f / (1.0f + expf(-v));
}

// f32 [K][N] -> bf16 [N][K] transpose (32x32 tiles)
__global__ void transpose_bf16_kernel(const float* __restrict__ src,
                                      bf16* __restrict__ dst, int K, int N) {
    __shared__ float t[32][33];
    const int k0 = blockIdx.x * 32, n0 = blockIdx.y * 32;
    const int tx = threadIdx.x, ty = threadIdx.y;
#pragma unroll
    for (int i = 0; i < 4; ++i) {
        int k = k0 + ty + i * 8;
        t[ty + i * 8][tx] = src[(size_t)k * N + n0 + tx];
    }
    __syncthreads();
#pragma unroll
    for (int i = 0; i < 4; ++i) {
        int nn = n0 + ty + i * 8;
        dst[(size_t)nn * K + k0 + tx] = (bf16)t[tx][ty + i * 8];
    }
}

__global__ __launch_bounds__(1024, 4)
void crvnn_main(const float* __restrict__ x, const float* __restrict__ inmask,
                const float* __restrict__ vSTART, const float* __restrict__ vEND,
                const float* __restrict__ b_init, const float* __restrict__ ln_g,
                const float* __restrict__ ln_b, const float* __restrict__ b_conv,
                const float* __restrict__ W_sc, const float* __restrict__ b_sc,
                const float* __restrict__ b_c1, const float* __restrict__ b_c2,
                const bf16* __restrict__ WbInit, const bf16* __restrict__ WbConv,
                const bf16* __restrict__ WbC1, const bf16* __restrict__ WbC2,
                float* __restrict__ out) {
    extern __shared__ char smem[];
    float* sSeq   = (float*)(smem + OFF_SEQ);
    bf16*  sSeqB  = (bf16*)(smem + OFF_SEQB);
    bf16*  sL1    = (bf16*)(smem + OFF_L1);
    bf16*  sR1    = (bf16*)(smem + OFF_R1);
    bf16*  sTmp   = (bf16*)(smem + OFF_TMP);
    bf16*  sTmp2  = (bf16*)(smem + OFF_TMP2);
    float* sTrans = (float*)(smem + OFF_TRANS);
    bf16*  sInter = (bf16*)(smem + OFF_INTER);
    float* sLp    = (float*)(smem + OFF_LP);
    bf16*  sLpB   = (bf16*)(smem + OFF_LPB);
    bf16*  sRpB   = (bf16*)(smem + OFF_RPB);
    float* sAct   = (float*)(smem + OFF_ACT);
    float* sTp    = (float*)(smem + OFF_TP);
    float* sTs    = (float*)(smem + OFF_TS);
    float* sIm    = (float*)(smem + OFF_IM);
    float* sSelp  = (float*)(smem + OFF_SELP);
    float* sLtm   = (float*)(smem + OFF_LTM);
    float* sEndm  = (float*)(smem + OFF_ENDM);
    float* sRem   = (float*)(smem + OFF_REM);

    const int tid  = threadIdx.x;
    const int lane = tid & 63;
    const int w    = tid >> 6;   // wave id 0..15
    const int l15  = lane & 15;
    const int l4   = lane >> 4;  // 0..3
    const int r32  = tid >> 5;   // row 0..31 (32 threads/row)
    const int q32  = tid & 31;
    const int n    = blockIdx.x; // batch

    // ------------- masks / selp / active init -------------
    if (tid < 32) {
        const int r = tid;
        auto IM31 = [&](int j) -> float { return (j <= 0) ? 1.f : inmask[n * 30 + (j - 1)]; };
        float im_ye = (r == 0) ? 1.f : IM31(r - 1);
        float im_ne = (r <= 30) ? IM31(r) : 0.f;
        float endm  = im_ye - im_ne;
        float ins   = (r == 0) ? 0.f : im_ye;
        float ltm   = (r < 31) ? (IM31(r) - ((r <= 29) ? IM31(r + 1) : 0.f)) : 0.f;
        float selp  = ins * im_ne * (1.f - ltm);
        sIm[r] = im_ye; sEndm[r] = endm; sSelp[r] = selp; sLtm[r] = ltm; sAct[r] = im_ye;
    }
    __syncthreads();

    // ------------- build seq_pre (bf16), 32 threads/row -------------
    {
        const int r = r32;
        const float em = sEndm[r];
#pragma unroll
        for (int k = 0; k < 8; ++k) {
            int c = q32 + 32 * k;
            float base = (r == 0) ? vSTART[c] : ((r <= 30) ? x[(size_t)(n * 30 + (r - 1)) * 256 + c] : 0.f);
            float v = em * vEND[c] + (1.f - em) * base;
            sSeqB[r * LDB + c] = (bf16)v;
        }
    }
    __syncthreads();

    // ------------- init GEMM: seq = LN(seq_pre @ W_init + b_init) * im -------------
    {
        f32x4 acc[2];
        acc[0] = f32x4{0.f,0.f,0.f,0.f}; acc[1] = f32x4{0.f,0.f,0.f,0.f};
        const int col = 16 * w + l15;
        for (int kt = 0; kt < 8; ++kt) {
            int kk = kt * 32 + l4 * 8;
            bf16x8 a0 = *(const bf16x8*)(sSeqB + l15 * LDB + kk);
            bf16x8 a1 = *(const bf16x8*)(sSeqB + (16 + l15) * LDB + kk);
            bf16x8 b = *(const bf16x8*)(WbInit + (size_t)col * 256 + kk);
            acc[0] = MFMA16(a0, b, acc[0]);
            acc[1] = MFMA16(a1, b, acc[1]);
        }
#pragma unroll
        for (int mt = 0; mt < 2; ++mt)
#pragma unroll
            for (int i = 0; i < 4; ++i) {
                int row = mt * 16 + l4 * 4 + i;
                sSeq[row * 256 + col] = acc[mt][i] + b_init[col];
            }
    }
    __syncthreads();
    {   // layernorm rows, * im (32 threads/row)
        const int r = r32;
        float s = 0.f, s2 = 0.f, vals[8];
#pragma unroll
        for (int k = 0; k < 8; ++k) {
            float v = sSeq[r * 256 + q32 + 32 * k];
            vals[k] = v; s += v; s2 += v * v;
        }
        for (int m = 1; m < 32; m <<= 1) { s += __shfl_xor(s, m); s2 += __shfl_xor(s2, m); }
        float mu = s * (1.f / 256.f);
        float var = s2 * (1.f / 256.f) - mu * mu;
        float rstd = rsqrtf(var + 1e-5f);
        float imr = sIm[r];
#pragma unroll
        for (int k = 0; k < 8; ++k) {
            int c = q32 + 32 * k;
            sSeq[r * 256 + c] = ((vals[k] - mu) * rstd * ln_g[c] + ln_b[c]) * imr;
        }
    }
    __syncthreads();

    // ==================== scan: 30 steps ====================
    for (int step = 0; step < 30; ++step) {
        // ---- phase 1: neighbor probs (wave 0), seqB refresh, zero ts ----
        if (tid < 32) {
            const int i = tid;
            for (int j = 0; j < 32; ++j) {
                sLp[i * 32 + j] = 0.f;
                sRpB[i * LDP + j] = (bf16)0.f; sLpB[i * LDP + j] = (bf16)0.f;
            }
            float cc = 0.f;
            for (int j = i + 1; j < 32; ++j) {
                float am = sAct[j] * sIm[j];
                float cp = cc; cc += am;
                float v = (cc > 1.f) ? fmaxf(1.f - cp, 0.f) : am;
                v *= sIm[j];
                sRpB[i * LDP + j] = (bf16)v;
            }
            cc = 0.f;
            for (int j = i - 1; j >= 0; --j) {
                float am = sAct[j] * sIm[j];
                float cp = cc; cc += am;
                float v = (cc > 1.f) ? fmaxf(1.f - cp, 0.f) : am;
                v *= sIm[j];
                sLp[i * 32 + j] = v; sLpB[i * LDP + j] = (bf16)v;
            }
            sTs[i] = 0.f;
            if (i == 0) {
                float rm = 0.f;
                for (int j = 0; j < 32; ++j) rm += sAct[j] * sSelp[j];
                *sRem = rm;
            }
        }
        {
            const int r = r32;
#pragma unroll
            for (int k = 0; k < 8; ++k) {
                int c = q32 + 32 * k;
                sSeqB[r * LDB + c] = (bf16)sSeq[r * 256 + c];
            }
        }
        __syncthreads();
        if (*sRem <= 0.01f) break;  // u == 0 -> remaining steps identity (exact)

        const int n0 = 16 * w;  // this wave's 16-col slice

        // ---- phase 2: L1 = Lp@seq, R1 = Rp@seq (1 n-tile per wave) ----
        {
            bf16x8 aL0 = *(const bf16x8*)(sLpB + l15 * LDP + l4 * 8);
            bf16x8 aL1v = *(const bf16x8*)(sLpB + (16 + l15) * LDP + l4 * 8);
            bf16x8 aR0 = *(const bf16x8*)(sRpB + l15 * LDP + l4 * 8);
            bf16x8 aR1v = *(const bf16x8*)(sRpB + (16 + l15) * LDP + l4 * 8);
            bf16x8 bx;
#pragma unroll
            for (int s2 = 0; s2 < 8; ++s2) bx[s2] = sSeqB[(l4 * 8 + s2) * LDB + n0 + l15];
            f32x4 accL[2], accR[2];
            accL[0] = f32x4{0.f,0.f,0.f,0.f}; accL[1] = f32x4{0.f,0.f,0.f,0.f};
            accR[0] = f32x4{0.f,0.f,0.f,0.f}; accR[1] = f32x4{0.f,0.f,0.f,0.f};
            accL[0] = MFMA16(aL0, bx, accL[0]);
            accL[1] = MFMA16(aL1v, bx, accL[1]);
            accR[0] = MFMA16(aR0, bx, accR[0]);
            accR[1] = MFMA16(aR1v, bx, accR[1]);
#pragma unroll
            for (int mt = 0; mt < 2; ++mt)
#pragma unroll
                for (int i = 0; i < 4; ++i) {
                    int row = mt * 16 + l4 * 4 + i, col = n0 + l15;
                    sL1[row * LDB + col] = (bf16)accL[mt][i];
                    sR1[row * LDB + col] = (bf16)accR[mt][i];
                }
        }
        __syncthreads();

        // ---- phase 3: L2 = Lp@L1 -> sTmp ; R2 = Rp@R1 -> sTmp2 ;
        //               inter = gelu([L1,seq] @ W_c1 + b_c1) ----
        {
            bf16x8 aL0 = *(const bf16x8*)(sLpB + l15 * LDP + l4 * 8);
            bf16x8 aL1v = *(const bf16x8*)(sLpB + (16 + l15) * LDP + l4 * 8);
            bf16x8 aR0 = *(const bf16x8*)(sRpB + l15 * LDP + l4 * 8);
            bf16x8 aR1v = *(const bf16x8*)(sRpB + (16 + l15) * LDP + l4 * 8);
            bf16x8 bxL, bxR;
#pragma unroll
            for (int s2 = 0; s2 < 8; ++s2) {
                bxL[s2] = sL1[(l4 * 8 + s2) * LDB + n0 + l15];
                bxR[s2] = sR1[(l4 * 8 + s2) * LDB + n0 + l15];
            }
            f32x4 acc2[2], acc3[2];
            acc2[0] = f32x4{0.f,0.f,0.f,0.f}; acc2[1] = f32x4{0.f,0.f,0.f,0.f};
            acc3[0] = f32x4{0.f,0.f,0.f,0.f}; acc3[1] = f32x4{0.f,0.f,0.f,0.f};
            acc2[0] = MFMA16(aL0, bxL, acc2[0]);
            acc2[1] = MFMA16(aL1v, bxL, acc2[1]);
            acc3[0] = MFMA16(aR0, bxR, acc3[0]);
            acc3[1] = MFMA16(aR1v, bxR, acc3[1]);
#pragma unroll
            for (int mt = 0; mt < 2; ++mt)
#pragma unroll
                for (int i = 0; i < 4; ++i) {
                    int row = mt * 16 + l4 * 4 + i, col = n0 + l15;
                    sTmp[row * LDB + col] = (bf16)acc2[mt][i];
                    sTmp2[row * LDB + col] = (bf16)acc3[mt][i];
                }
            // c1 GEMM: 32 cols per wave
            f32x4 c1a[2][2];
#pragma unroll
            for (int mt = 0; mt < 2; ++mt)
#pragma unroll
                for (int nt = 0; nt < 2; ++nt) c1a[mt][nt] = f32x4{0.f,0.f,0.f,0.f};
            for (int kt = 0; kt < 16; ++kt) {
                const bf16* Ab = (kt < 8) ? sL1 : sSeqB;
                int kk = (kt & 7) * 32 + l4 * 8;
                bf16x8 a0 = *(const bf16x8*)(Ab + l15 * LDB + kk);
                bf16x8 a1 = *(const bf16x8*)(Ab + (16 + l15) * LDB + kk);
#pragma unroll
                for (int nt = 0; nt < 2; ++nt) {
                    bf16x8 b = *(const bf16x8*)(WbC1 + (size_t)(32 * w + nt * 16 + l15) * 512 + kt * 32 + l4 * 8);
                    c1a[0][nt] = MFMA16(a0, b, c1a[0][nt]);
                    c1a[1][nt] = MFMA16(a1, b, c1a[1][nt]);
                }
            }
#pragma unroll
            for (int mt = 0; mt < 2; ++mt)
#pragma unroll
                for (int nt = 0; nt < 2; ++nt)
#pragma unroll
                    for (int i = 0; i < 4; ++i) {
                        int row = mt * 16 + l4 * 4 + i, col = 32 * w + nt * 16 + l15;
                        float v = c1a[mt][nt][i] + b_c1[col];
                        sInter[row * LDI + col] = (bf16)gelu_f(v);
                    }
        }
        __syncthreads();

        // ---- phase 4: conv over 5 slices + ts = gelu(h) @ W_sc ----
        {
            f32x4 cva[2];
            cva[0] = f32x4{0.f,0.f,0.f,0.f}; cva[1] = f32x4{0.f,0.f,0.f,0.f};
            const bf16* slices[5] = { sTmp, sL1, sSeqB, sR1, sTmp2 };
            const int col = n0 + l15;
#pragma unroll
            for (int sl = 0; sl < 5; ++sl) {
                const bf16* Ab = slices[sl];
                for (int kt = 0; kt < 8; ++kt) {
                    int kk = kt * 32 + l4 * 8;
                    bf16x8 a0 = *(const bf16x8*)(Ab + l15 * LDB + kk);
                    bf16x8 a1 = *(const bf16x8*)(Ab + (16 + l15) * LDB + kk);
                    bf16x8 b = *(const bf16x8*)(WbConv + (size_t)col * 1280 + sl * 256 + kk);
                    cva[0] = MFMA16(a0, b, cva[0]);
                    cva[1] = MFMA16(a1, b, cva[1]);
                }
            }
#pragma unroll
            for (int mt = 0; mt < 2; ++mt)
#pragma unroll
                for (int i = 0; i < 4; ++i) {
                    int row = mt * 16 + l4 * 4 + i;
                    float hv = gelu_f(cva[mt][i] + b_conv[col]);
                    float p = hv * W_sc[col];
                    p += __shfl_xor(p, 1); p += __shfl_xor(p, 2);
                    p += __shfl_xor(p, 4); p += __shfl_xor(p, 8);
                    if (l15 == 0) atomicAdd(&sTs[row], p);
                }
        }
        __syncthreads();

        // ---- phase 5: tp ; c2 GEMM ; gates -> trans_pre ----
        if (tid < 32) {
            float t = sTs[tid] + b_sc[0];
            sTp[tid] = sSelp[tid] * sigm_f(t);
        }
        {
            f32x4 c2a[2][4];
#pragma unroll
            for (int mt = 0; mt < 2; ++mt)
#pragma unroll
                for (int g = 0; g < 4; ++g) c2a[mt][g] = f32x4{0.f,0.f,0.f,0.f};
            for (int kt = 0; kt < 16; ++kt) {
                int kk = kt * 32 + l4 * 8;
                bf16x8 a0 = *(const bf16x8*)(sInter + l15 * LDI + kk);
                bf16x8 a1 = *(const bf16x8*)(sInter + (16 + l15) * LDI + kk);
#pragma unroll
                for (int g = 0; g < 4; ++g) {
                    int col = g * 256 + n0 + l15;
                    bf16x8 b = *(const bf16x8*)(WbC2 + (size_t)col * 512 + kk);
                    c2a[0][g] = MFMA16(a0, b, c2a[0][g]);
                    c2a[1][g] = MFMA16(a1, b, c2a[1][g]);
                }
            }
#pragma unroll
            for (int mt = 0; mt < 2; ++mt)
#pragma unroll
                for (int i = 0; i < 4; ++i) {
                    int row = mt * 16 + l4 * 4 + i;
                    int d = n0 + l15;
                    float c0 = c2a[mt][0][i] + b_c2[d];
                    float c1v = c2a[mt][1][i] + b_c2[256 + d];
                    float c2v = c2a[mt][2][i] + b_c2[512 + d];
                    float c3v = c2a[mt][3][i] + b_c2[768 + d];
                    float g0 = sigm_f(c0), g1 = sigm_f(c1v), g2 = sigm_f(c2v);
                    float lc = (float)sL1[row * LDB + d];
                    float sv = sSeq[row * 256 + d];
                    sTrans[row * 256 + d] = g0 * lc + g1 * sv + g2 * c3v;
                }
        }
        __syncthreads();

        // ---- phase 6: trans = LN(trans_pre); seq update; active update ----
        {
            const int r = r32;
            float s = 0.f, s2 = 0.f, vals[8];
#pragma unroll
            for (int k = 0; k < 8; ++k) {
                float v = sTrans[r * 256 + q32 + 32 * k];
                vals[k] = v; s += v; s2 += v * v;
            }
            for (int m = 1; m < 32; m <<= 1) { s += __shfl_xor(s, m); s2 += __shfl_xor(s2, m); }
            float mu = s * (1.f / 256.f);
            float var = s2 * (1.f / 256.f) - mu * mu;
            float rstd = rsqrtf(var + 1e-5f);
            float tpv = sTp[r], imr = sIm[r];
#pragma unroll
            for (int k = 0; k < 8; ++k) {
                int c = q32 + 32 * k;
                float tr = (vals[k] - mu) * rstd * ln_g[c] + ln_b[c];
                float sv = sSeq[r * 256 + c];
                sSeq[r * 256 + c] = (tpv * tr + (1.f - tpv) * sv) * imr;
            }
        }
        if (tid < 32) {
            const int j = tid;
            float cons = 0.f;
            for (int i = 0; i < 32; ++i) cons += sLp[i * 32 + j] * sTp[i];
            sAct[j] = fmaxf(sAct[j] - cons, 0.f);
        }
        __syncthreads();
    }

    // ---- output: sum_j ltm[j] * seq[j] ----
    if (tid < 256) {
        float o = 0.f;
        for (int j = 0; j < 32; ++j) o += sLtm[j] * sSeq[j * 256 + tid];
        out[(size_t)n * 256 + tid] = o;
    }
}

extern "C" void kernel_launch(void* const* d_in, const int* in_sizes, int n_in,
                              void* d_out, int out_size, void* d_ws, size_t ws_size,
                              hipStream_t stream) {
    const float* x       = (const float*)d_in[0];
    const float* inmask  = (const float*)d_in[1];
    const float* vSTART  = (const float*)d_in[2];
    const float* vEND    = (const float*)d_in[3];
    const float* W_init  = (const float*)d_in[4];
    const float* b_init  = (const float*)d_in[5];
    const float* ln_g    = (const float*)d_in[6];
    const float* ln_b    = (const float*)d_in[7];
    const float* W_conv  = (const float*)d_in[8];
    const float* b_conv  = (const float*)d_in[9];
    const float* W_sc    = (const float*)d_in[10];
    const float* b_sc    = (const float*)d_in[11];
    const float* W_c1    = (const float*)d_in[12];
    const float* b_c1    = (const float*)d_in[13];
    const float* W_c2    = (const float*)d_in[14];
    const float* b_c2    = (const float*)d_in[15];
    float* out = (float*)d_out;

    bf16* WbInit = (bf16*)d_ws;                 // 256 x 256
    bf16* WbConv = WbInit + 256 * 256;          // 256 x 1280
    bf16* WbC1   = WbConv + 256 * 1280;         // 512 x 512
    bf16* WbC2   = WbC1 + 512 * 512;            // 1024 x 512

    dim3 tb(32, 8);
    transpose_bf16_kernel<<<dim3(256 / 32, 256 / 32), tb, 0, stream>>>(W_init, WbInit, 256, 256);
    transpose_bf16_kernel<<<dim3(1280 / 32, 256 / 32), tb, 0, stream>>>(W_conv, WbConv, 1280, 256);
    transpose_bf16_kernel<<<dim3(512 / 32, 512 / 32), tb, 0, stream>>>(W_c1, WbC1, 512, 512);
    transpose_bf16_kernel<<<dim3(512 / 32, 1024 / 32), tb, 0, stream>>>(W_c2, WbC2, 512, 1024);

    hipFuncSetAttribute((const void*)crvnn_main,
                        hipFuncAttributeMaxDynamicSharedMemorySize, SMEM_BYTES);
    crvnn_main<<<dim3(16), dim3(1024), SMEM_BYTES, stream>>>(
        x, inmask, vSTART, vEND, b_init, ln_g, ln_b, b_conv, W_sc, b_sc,
        b_c1, b_c2, WbInit, WbConv, WbC1, WbC2, out);
}

// Round 6
// 2948.000 us; speedup vs baseline: 1.0212x; 1.0212x over previous
//
#include <hip/hip_runtime.h>
#include <hip/hip_bf16.h>
#include <math.h>

// ------------------------------------------------------------------
// CRvNN forward on MI355X. Round 6: drain-free phase barriers
// (lgkmcnt-only, weight loads stay in flight across phases), full
// unroll of weight-GEMM k-loops (deep MLP vs L2 latency), atomic-free
// ts reduction. 1024 threads/block, 1 block/batch, state in LDS.
// ------------------------------------------------------------------

typedef __bf16 bf16;
typedef bf16  bf16x8 __attribute__((ext_vector_type(8)));
typedef float f32x4  __attribute__((ext_vector_type(4)));

#define MFMA16(a,b,c) __builtin_amdgcn_mfma_f32_16x16x32_bf16((a),(b),(c),0,0,0)

// Barrier with LDS-only drain: weight loads (global->reg, read-only)
// legally remain in flight across phase boundaries. All inter-wave
// data hazards in this kernel flow through LDS (lgkmcnt).
__device__ __forceinline__ void bar_lds() {
    asm volatile("s_waitcnt lgkmcnt(0)\n\ts_barrier" ::: "memory");
}

constexpr int LDB = 264;  // bf16 row stride for 256-wide tiles
constexpr int LDI = 520;  // bf16 row stride for 512-wide inter
constexpr int LDP = 40;   // bf16 row stride for 32x32 prob mats

// LDS arena byte offsets (total 162816 <= 163840)
constexpr int OFF_SEQ   = 0;        // f32 [32][256]  32768
constexpr int OFF_SEQB  = 32768;    // bf16 [32][264] 16896
constexpr int OFF_L1    = 49664;    // bf16 [32][264] 16896
constexpr int OFF_R1    = 66560;    // bf16 [32][264] 16896 } sTrans f32 aliases
constexpr int OFF_TMP   = 83456;    // bf16 [32][264] 16896 } R1+TMP (dead by then)
constexpr int OFF_TRANS = 66560;    // f32 [32][256]  32768 (alias)
constexpr int OFF_INTER = 100352;   // bf16 [32][520] 33280
constexpr int OFF_TMP2  = 133632;   // bf16 [32][264] 16896
constexpr int OFF_LP    = 150528;   // f32 [32][32]   4096 (consumed matvec)
constexpr int OFF_LPB   = 154624;   // bf16 [32][40]  2560
constexpr int OFF_RPB   = 157184;   // bf16 [32][40]  2560
constexpr int OFF_ACT   = 159744;   // f32 [32]
constexpr int OFF_TP    = 159872;   // f32 [32]
constexpr int OFF_IM    = 160000;   // f32 [32]
constexpr int OFF_SELP  = 160128;   // f32 [32]
constexpr int OFF_LTM   = 160256;   // f32 [32]
constexpr int OFF_ENDM  = 160384;   // f32 [32]
constexpr int OFF_REM   = 160512;   // f32 [1]
constexpr int OFF_TSP   = 160640;   // f32 [32][17] = 2176
constexpr int SMEM_BYTES = 162816;

__device__ __forceinline__ float gelu_f(float v) {
    return 0.5f * v * (1.0f + erff(v * 0.70710678118654752f));
}
__device__ __forceinline__ float sigm_f(float v) {
    return 1.0f / (1.0f + expf(-v));
}

// f32 [K][N] -> bf16 [N][K] transpose (32x32 tiles)
__global__ void transpose_bf16_kernel(const float* __restrict__ src,
                                      bf16* __restrict__ dst, int K, int N) {
    __shared__ float t[32][33];
    const int k0 = blockIdx.x * 32, n0 = blockIdx.y * 32;
    const int tx = threadIdx.x, ty = threadIdx.y;
#pragma unroll
    for (int i = 0; i < 4; ++i) {
        int k = k0 + ty + i * 8;
        t[ty + i * 8][tx] = src[(size_t)k * N + n0 + tx];
    }
    __syncthreads();
#pragma unroll
    for (int i = 0; i < 4; ++i) {
        int nn = n0 + ty + i * 8;
        dst[(size_t)nn * K + k0 + tx] = (bf16)t[tx][ty + i * 8];
    }
}

__global__ __launch_bounds__(1024, 4)
void crvnn_main(const float* __restrict__ x, const float* __restrict__ inmask,
                const float* __restrict__ vSTART, const float* __restrict__ vEND,
                const float* __restrict__ b_init, const float* __restrict__ ln_g,
                const float* __restrict__ ln_b, const float* __restrict__ b_conv,
                const float* __restrict__ W_sc, const float* __restrict__ b_sc,
                const float* __restrict__ b_c1, const float* __restrict__ b_c2,
                const bf16* __restrict__ WbInit, const bf16* __restrict__ WbConv,
                const bf16* __restrict__ WbC1, const bf16* __restrict__ WbC2,
                float* __restrict__ out) {
    extern __shared__ char smem[];
    float* sSeq   = (float*)(smem + OFF_SEQ);
    bf16*  sSeqB  = (bf16*)(smem + OFF_SEQB);
    bf16*  sL1    = (bf16*)(smem + OFF_L1);
    bf16*  sR1    = (bf16*)(smem + OFF_R1);
    bf16*  sTmp   = (bf16*)(smem + OFF_TMP);
    bf16*  sTmp2  = (bf16*)(smem + OFF_TMP2);
    float* sTrans = (float*)(smem + OFF_TRANS);
    bf16*  sInter = (bf16*)(smem + OFF_INTER);
    float* sLp    = (float*)(smem + OFF_LP);
    bf16*  sLpB   = (bf16*)(smem + OFF_LPB);
    bf16*  sRpB   = (bf16*)(smem + OFF_RPB);
    float* sAct   = (float*)(smem + OFF_ACT);
    float* sTp    = (float*)(smem + OFF_TP);
    float* sIm    = (float*)(smem + OFF_IM);
    float* sSelp  = (float*)(smem + OFF_SELP);
    float* sLtm   = (float*)(smem + OFF_LTM);
    float* sEndm  = (float*)(smem + OFF_ENDM);
    float* sRem   = (float*)(smem + OFF_REM);
    float* sTsP   = (float*)(smem + OFF_TSP);   // [32][17]

    const int tid  = threadIdx.x;
    const int lane = tid & 63;
    const int w    = tid >> 6;   // wave id 0..15
    const int l15  = lane & 15;
    const int l4   = lane >> 4;  // 0..3
    const int r32  = tid >> 5;   // row 0..31 (32 threads/row)
    const int q32  = tid & 31;
    const int n    = blockIdx.x; // batch

    // ------------- masks / selp / active init -------------
    if (tid < 32) {
        const int r = tid;
        auto IM31 = [&](int j) -> float { return (j <= 0) ? 1.f : inmask[n * 30 + (j - 1)]; };
        float im_ye = (r == 0) ? 1.f : IM31(r - 1);
        float im_ne = (r <= 30) ? IM31(r) : 0.f;
        float endm  = im_ye - im_ne;
        float ins   = (r == 0) ? 0.f : im_ye;
        float ltm   = (r < 31) ? (IM31(r) - ((r <= 29) ? IM31(r + 1) : 0.f)) : 0.f;
        float selp  = ins * im_ne * (1.f - ltm);
        sIm[r] = im_ye; sEndm[r] = endm; sSelp[r] = selp; sLtm[r] = ltm; sAct[r] = im_ye;
    }
    bar_lds();

    // ------------- build seq_pre (bf16), 32 threads/row -------------
    {
        const int r = r32;
        const float em = sEndm[r];
#pragma unroll
        for (int k = 0; k < 8; ++k) {
            int c = q32 + 32 * k;
            float base = (r == 0) ? vSTART[c] : ((r <= 30) ? x[(size_t)(n * 30 + (r - 1)) * 256 + c] : 0.f);
            float v = em * vEND[c] + (1.f - em) * base;
            sSeqB[r * LDB + c] = (bf16)v;
        }
    }
    bar_lds();

    // ------------- init GEMM: seq = LN(seq_pre @ W_init + b_init) * im -------------
    {
        f32x4 acc[2];
        acc[0] = f32x4{0.f,0.f,0.f,0.f}; acc[1] = f32x4{0.f,0.f,0.f,0.f};
        const int col = 16 * w + l15;
#pragma unroll
        for (int kt = 0; kt < 8; ++kt) {
            int kk = kt * 32 + l4 * 8;
            bf16x8 a0 = *(const bf16x8*)(sSeqB + l15 * LDB + kk);
            bf16x8 a1 = *(const bf16x8*)(sSeqB + (16 + l15) * LDB + kk);
            bf16x8 b = *(const bf16x8*)(WbInit + (size_t)col * 256 + kk);
            acc[0] = MFMA16(a0, b, acc[0]);
            acc[1] = MFMA16(a1, b, acc[1]);
        }
#pragma unroll
        for (int mt = 0; mt < 2; ++mt)
#pragma unroll
            for (int i = 0; i < 4; ++i) {
                int row = mt * 16 + l4 * 4 + i;
                sSeq[row * 256 + col] = acc[mt][i] + b_init[col];
            }
    }
    bar_lds();
    {   // layernorm rows, * im (32 threads/row)
        const int r = r32;
        float s = 0.f, s2 = 0.f, vals[8];
#pragma unroll
        for (int k = 0; k < 8; ++k) {
            float v = sSeq[r * 256 + q32 + 32 * k];
            vals[k] = v; s += v; s2 += v * v;
        }
        for (int m = 1; m < 32; m <<= 1) { s += __shfl_xor(s, m); s2 += __shfl_xor(s2, m); }
        float mu = s * (1.f / 256.f);
        float var = s2 * (1.f / 256.f) - mu * mu;
        float rstd = rsqrtf(var + 1e-5f);
        float imr = sIm[r];
#pragma unroll
        for (int k = 0; k < 8; ++k) {
            int c = q32 + 32 * k;
            sSeq[r * 256 + c] = ((vals[k] - mu) * rstd * ln_g[c] + ln_b[c]) * imr;
        }
    }
    bar_lds();

    // ==================== scan: 30 steps ====================
    for (int step = 0; step < 30; ++step) {
        // ---- phase 1: neighbor probs (wave 0), seqB refresh ----
        if (tid < 32) {
            const int i = tid;
            for (int j = 0; j < 32; ++j) {
                sLp[i * 32 + j] = 0.f;
                sRpB[i * LDP + j] = (bf16)0.f; sLpB[i * LDP + j] = (bf16)0.f;
            }
            float cc = 0.f;
            for (int j = i + 1; j < 32; ++j) {
                float am = sAct[j] * sIm[j];
                float cp = cc; cc += am;
                float v = (cc > 1.f) ? fmaxf(1.f - cp, 0.f) : am;
                v *= sIm[j];
                sRpB[i * LDP + j] = (bf16)v;
            }
            cc = 0.f;
            for (int j = i - 1; j >= 0; --j) {
                float am = sAct[j] * sIm[j];
                float cp = cc; cc += am;
                float v = (cc > 1.f) ? fmaxf(1.f - cp, 0.f) : am;
                v *= sIm[j];
                sLp[i * 32 + j] = v; sLpB[i * LDP + j] = (bf16)v;
            }
            if (i == 0) {
                float rm = 0.f;
                for (int j = 0; j < 32; ++j) rm += sAct[j] * sSelp[j];
                *sRem = rm;
            }
        }
        {
            const int r = r32;
#pragma unroll
            for (int k = 0; k < 8; ++k) {
                int c = q32 + 32 * k;
                sSeqB[r * LDB + c] = (bf16)sSeq[r * 256 + c];
            }
        }
        bar_lds();
        if (*sRem <= 0.01f) break;  // u == 0 -> remaining steps identity (exact)

        const int n0 = 16 * w;  // this wave's 16-col slice

        // ---- phase 2: L1 = Lp@seq, R1 = Rp@seq ----
        {
            bf16x8 aL0 = *(const bf16x8*)(sLpB + l15 * LDP + l4 * 8);
            bf16x8 aL1v = *(const bf16x8*)(sLpB + (16 + l15) * LDP + l4 * 8);
            bf16x8 aR0 = *(const bf16x8*)(sRpB + l15 * LDP + l4 * 8);
            bf16x8 aR1v = *(const bf16x8*)(sRpB + (16 + l15) * LDP + l4 * 8);
            bf16x8 bx;
#pragma unroll
            for (int s2 = 0; s2 < 8; ++s2) bx[s2] = sSeqB[(l4 * 8 + s2) * LDB + n0 + l15];
            f32x4 accL[2], accR[2];
            accL[0] = f32x4{0.f,0.f,0.f,0.f}; accL[1] = f32x4{0.f,0.f,0.f,0.f};
            accR[0] = f32x4{0.f,0.f,0.f,0.f}; accR[1] = f32x4{0.f,0.f,0.f,0.f};
            accL[0] = MFMA16(aL0, bx, accL[0]);
            accL[1] = MFMA16(aL1v, bx, accL[1]);
            accR[0] = MFMA16(aR0, bx, accR[0]);
            accR[1] = MFMA16(aR1v, bx, accR[1]);
#pragma unroll
            for (int mt = 0; mt < 2; ++mt)
#pragma unroll
                for (int i = 0; i < 4; ++i) {
                    int row = mt * 16 + l4 * 4 + i, col = n0 + l15;
                    sL1[row * LDB + col] = (bf16)accL[mt][i];
                    sR1[row * LDB + col] = (bf16)accR[mt][i];
                }
        }
        bar_lds();

        // ---- phase 3: L2 -> sTmp ; R2 -> sTmp2 ; inter = gelu([L1,seq]@W_c1+b) ----
        {
            bf16x8 aL0 = *(const bf16x8*)(sLpB + l15 * LDP + l4 * 8);
            bf16x8 aL1v = *(const bf16x8*)(sLpB + (16 + l15) * LDP + l4 * 8);
            bf16x8 aR0 = *(const bf16x8*)(sRpB + l15 * LDP + l4 * 8);
            bf16x8 aR1v = *(const bf16x8*)(sRpB + (16 + l15) * LDP + l4 * 8);
            bf16x8 bxL, bxR;
#pragma unroll
            for (int s2 = 0; s2 < 8; ++s2) {
                bxL[s2] = sL1[(l4 * 8 + s2) * LDB + n0 + l15];
                bxR[s2] = sR1[(l4 * 8 + s2) * LDB + n0 + l15];
            }
            f32x4 acc2[2], acc3[2];
            acc2[0] = f32x4{0.f,0.f,0.f,0.f}; acc2[1] = f32x4{0.f,0.f,0.f,0.f};
            acc3[0] = f32x4{0.f,0.f,0.f,0.f}; acc3[1] = f32x4{0.f,0.f,0.f,0.f};
            acc2[0] = MFMA16(aL0, bxL, acc2[0]);
            acc2[1] = MFMA16(aL1v, bxL, acc2[1]);
            acc3[0] = MFMA16(aR0, bxR, acc3[0]);
            acc3[1] = MFMA16(aR1v, bxR, acc3[1]);
#pragma unroll
            for (int mt = 0; mt < 2; ++mt)
#pragma unroll
                for (int i = 0; i < 4; ++i) {
                    int row = mt * 16 + l4 * 4 + i, col = n0 + l15;
                    sTmp[row * LDB + col] = (bf16)acc2[mt][i];
                    sTmp2[row * LDB + col] = (bf16)acc3[mt][i];
                }
            // c1 GEMM: 32 cols per wave
            f32x4 c1a[2][2];
#pragma unroll
            for (int mt = 0; mt < 2; ++mt)
#pragma unroll
                for (int nt = 0; nt < 2; ++nt) c1a[mt][nt] = f32x4{0.f,0.f,0.f,0.f};
#pragma unroll
            for (int kt = 0; kt < 16; ++kt) {
                const bf16* Ab = (kt < 8) ? sL1 : sSeqB;
                int kk = (kt & 7) * 32 + l4 * 8;
                bf16x8 a0 = *(const bf16x8*)(Ab + l15 * LDB + kk);
                bf16x8 a1 = *(const bf16x8*)(Ab + (16 + l15) * LDB + kk);
#pragma unroll
                for (int nt = 0; nt < 2; ++nt) {
                    bf16x8 b = *(const bf16x8*)(WbC1 + (size_t)(32 * w + nt * 16 + l15) * 512 + kt * 32 + l4 * 8);
                    c1a[0][nt] = MFMA16(a0, b, c1a[0][nt]);
                    c1a[1][nt] = MFMA16(a1, b, c1a[1][nt]);
                }
            }
#pragma unroll
            for (int mt = 0; mt < 2; ++mt)
#pragma unroll
                for (int nt = 0; nt < 2; ++nt)
#pragma unroll
                    for (int i = 0; i < 4; ++i) {
                        int row = mt * 16 + l4 * 4 + i, col = 32 * w + nt * 16 + l15;
                        float v = c1a[mt][nt][i] + b_c1[col];
                        sInter[row * LDI + col] = (bf16)gelu_f(v);
                    }
        }
        bar_lds();

        // ---- phase 4: conv over 5 slices + ts partials (atomic-free) ----
        {
            f32x4 cva[2];
            cva[0] = f32x4{0.f,0.f,0.f,0.f}; cva[1] = f32x4{0.f,0.f,0.f,0.f};
            const bf16* slices[5] = { sTmp, sL1, sSeqB, sR1, sTmp2 };
            const int col = n0 + l15;
#pragma unroll
            for (int sl = 0; sl < 5; ++sl) {
                const bf16* Ab = slices[sl];
#pragma unroll
                for (int kt = 0; kt < 8; ++kt) {
                    int kk = kt * 32 + l4 * 8;
                    bf16x8 a0 = *(const bf16x8*)(Ab + l15 * LDB + kk);
                    bf16x8 a1 = *(const bf16x8*)(Ab + (16 + l15) * LDB + kk);
                    bf16x8 b = *(const bf16x8*)(WbConv + (size_t)col * 1280 + sl * 256 + kk);
                    cva[0] = MFMA16(a0, b, cva[0]);
                    cva[1] = MFMA16(a1, b, cva[1]);
                }
            }
#pragma unroll
            for (int mt = 0; mt < 2; ++mt)
#pragma unroll
                for (int i = 0; i < 4; ++i) {
                    int row = mt * 16 + l4 * 4 + i;
                    float hv = gelu_f(cva[mt][i] + b_conv[col]);
                    float p = hv * W_sc[col];
                    p += __shfl_xor(p, 1); p += __shfl_xor(p, 2);
                    p += __shfl_xor(p, 4); p += __shfl_xor(p, 8);
                    if (l15 == 0) sTsP[row * 17 + w] = p;  // unique (row, wave) slot
                }
        }
        bar_lds();

        // ---- phase 5: tp ; c2 GEMM ; gates -> trans_pre ----
        if (tid < 32) {
            float t = b_sc[0];
#pragma unroll
            for (int ww = 0; ww < 16; ++ww) t += sTsP[tid * 17 + ww];
            sTp[tid] = sSelp[tid] * sigm_f(t);
        }
        {
            f32x4 c2a[2][4];
#pragma unroll
            for (int mt = 0; mt < 2; ++mt)
#pragma unroll
                for (int g = 0; g < 4; ++g) c2a[mt][g] = f32x4{0.f,0.f,0.f,0.f};
#pragma unroll
            for (int kt = 0; kt < 16; ++kt) {
                int kk = kt * 32 + l4 * 8;
                bf16x8 a0 = *(const bf16x8*)(sInter + l15 * LDI + kk);
                bf16x8 a1 = *(const bf16x8*)(sInter + (16 + l15) * LDI + kk);
#pragma unroll
                for (int g = 0; g < 4; ++g) {
                    int col = g * 256 + n0 + l15;
                    bf16x8 b = *(const bf16x8*)(WbC2 + (size_t)col * 512 + kk);
                    c2a[0][g] = MFMA16(a0, b, c2a[0][g]);
                    c2a[1][g] = MFMA16(a1, b, c2a[1][g]);
                }
            }
#pragma unroll
            for (int mt = 0; mt < 2; ++mt)
#pragma unroll
                for (int i = 0; i < 4; ++i) {
                    int row = mt * 16 + l4 * 4 + i;
                    int d = n0 + l15;
                    float c0 = c2a[mt][0][i] + b_c2[d];
                    float c1v = c2a[mt][1][i] + b_c2[256 + d];
                    float c2v = c2a[mt][2][i] + b_c2[512 + d];
                    float c3v = c2a[mt][3][i] + b_c2[768 + d];
                    float g0 = sigm_f(c0), g1 = sigm_f(c1v), g2 = sigm_f(c2v);
                    float lc = (float)sL1[row * LDB + d];
                    float sv = sSeq[row * 256 + d];
                    sTrans[row * 256 + d] = g0 * lc + g1 * sv + g2 * c3v;
                }
        }
        bar_lds();

        // ---- phase 6: trans = LN(trans_pre); seq update; active update ----
        {
            const int r = r32;
            float s = 0.f, s2 = 0.f, vals[8];
#pragma unroll
            for (int k = 0; k < 8; ++k) {
                float v = sTrans[r * 256 + q32 + 32 * k];
                vals[k] = v; s += v; s2 += v * v;
            }
            for (int m = 1; m < 32; m <<= 1) { s += __shfl_xor(s, m); s2 += __shfl_xor(s2, m); }
            float mu = s * (1.f / 256.f);
            float var = s2 * (1.f / 256.f) - mu * mu;
            float rstd = rsqrtf(var + 1e-5f);
            float tpv = sTp[r], imr = sIm[r];
#pragma unroll
            for (int k = 0; k < 8; ++k) {
                int c = q32 + 32 * k;
                float tr = (vals[k] - mu) * rstd * ln_g[c] + ln_b[c];
                float sv = sSeq[r * 256 + c];
                sSeq[r * 256 + c] = (tpv * tr + (1.f - tpv) * sv) * imr;
            }
        }
        if (tid < 32) {
            const int j = tid;
            float cons = 0.f;
            for (int i = 0; i < 32; ++i) cons += sLp[i * 32 + j] * sTp[i];
            sAct[j] = fmaxf(sAct[j] - cons, 0.f);
        }
        bar_lds();
    }

    // ---- output: sum_j ltm[j] * seq[j] ----
    if (tid < 256) {
        float o = 0.f;
        for (int j = 0; j < 32; ++j) o += sLtm[j] * sSeq[j * 256 + tid];
        out[(size_t)n * 256 + tid] = o;
    }
}

extern "C" void kernel_launch(void* const* d_in, const int* in_sizes, int n_in,
                              void* d_out, int out_size, void* d_ws, size_t ws_size,
                              hipStream_t stream) {
    const float* x       = (const float*)d_in[0];
    const float* inmask  = (const float*)d_in[1];
    const float* vSTART  = (const float*)d_in[2];
    const float* vEND    = (const float*)d_in[3];
    const float* W_init  = (const float*)d_in[4];
    const float* b_init  = (const float*)d_in[5];
    const float* ln_g    = (const float*)d_in[6];
    const float* ln_b    = (const float*)d_in[7];
    const float* W_conv  = (const float*)d_in[8];
    const float* b_conv  = (const float*)d_in[9];
    const float* W_sc    = (const float*)d_in[10];
    const float* b_sc    = (const float*)d_in[11];
    const float* W_c1    = (const float*)d_in[12];
    const float* b_c1    = (const float*)d_in[13];
    const float* W_c2    = (const float*)d_in[14];
    const float* b_c2    = (const float*)d_in[15];
    float* out = (float*)d_out;

    bf16* WbInit = (bf16*)d_ws;                 // 256 x 256
    bf16* WbConv = WbInit + 256 * 256;          // 256 x 1280
    bf16* WbC1   = WbConv + 256 * 1280;         // 512 x 512
    bf16* WbC2   = WbC1 + 512 * 512;            // 1024 x 512

    dim3 tb(32, 8);
    transpose_bf16_kernel<<<dim3(256 / 32, 256 / 32), tb, 0, stream>>>(W_init, WbInit, 256, 256);
    transpose_bf16_kernel<<<dim3(1280 / 32, 256 / 32), tb, 0, stream>>>(W_conv, WbConv, 1280, 256);
    transpose_bf16_kernel<<<dim3(512 / 32, 512 / 32), tb, 0, stream>>>(W_c1, WbC1, 512, 512);
    transpose_bf16_kernel<<<dim3(512 / 32, 1024 / 32), tb, 0, stream>>>(W_c2, WbC2, 512, 1024);

    hipFuncSetAttribute((const void*)crvnn_main,
                        hipFuncAttributeMaxDynamicSharedMemorySize, SMEM_BYTES);
    crvnn_main<<<dim3(16), dim3(1024), SMEM_BYTES, stream>>>(
        x, inmask, vSTART, vEND, b_init, ln_g, ln_b, b_conv, W_sc, b_sc,
        b_c1, b_c2, WbInit, WbConv, WbC1, WbC2, out);
}